// Round 11
// baseline (302.757 us; speedup 1.0000x reference)
//
#include <hip/hip_runtime.h>

#define N_ROWS 4096
#define IN_F   4096
#define OUT_F  4096
#define C_CB   256
#define KDIM   4096   // C_CB * 16

typedef short bf16x8 __attribute__((ext_vector_type(8)));
typedef float f32x4  __attribute__((ext_vector_type(4)));

union ABFrag { unsigned long long u[2]; bf16x8 v; };

__device__ __forceinline__ unsigned int f2bf(float f) {
    unsigned int u = __builtin_bit_cast(unsigned int, f);
    return (u + 0x7FFFu + ((u >> 16) & 1u)) >> 16;   // RNE
}

// ---------------- Kernel 1: fused prep ----------------
// blocks [0, N_ROWS): tree descent, R3-proven LDS-staged gather form
// blocks [N_ROWS, N_ROWS+CVT_BLOCKS): lut fp32 -> bf16
// Fused residual ~34us (R7/R9 twice-confirmed) vs ~45 separate.
#define CVT_BLOCKS ((OUT_F * KDIM) / (256 * 8))   // 8192

__global__ __launch_bounds__(256) void k_prep(const float* __restrict__ input,
                                              const int* __restrict__ dims,
                                              const float* __restrict__ thr,
                                              unsigned char* __restrict__ idx4,
                                              const float* __restrict__ lut,
                                              unsigned short* __restrict__ lutb) {
    __shared__ float rowS[IN_F];         // 16 KB
    __shared__ float thrS[C_CB * 15];    // 15 KB
    __shared__ int   dimS[C_CB * 4];     // 4 KB
    const int b = blockIdx.x;
    const int t = threadIdx.x;

    if (b < N_ROWS) {
        const int n = b;
        #pragma unroll
        for (int i = 0; i < 4; i++) dimS[i * 256 + t] = dims[i * 256 + t];
        #pragma unroll
        for (int i = 0; i < 15; i++) thrS[i * 256 + t] = thr[i * 256 + t];
        const float* row = input + (size_t)n * IN_F;
        #pragma unroll
        for (int i = 0; i < 4; i++) {
            float4 v = *(const float4*)(row + i * 1024 + t * 4);
            *(float4*)(rowS + i * 1024 + t * 4) = v;
        }
        __syncthreads();

        const int c = t;
        int4 d = *(const int4*)(dimS + c * 4);
        const float* th = thrS + c * 15;
        float x0 = rowS[d.x], x1 = rowS[d.y], x2 = rowS[d.z], x3 = rowS[d.w];
        int b0 = x0 > th[0];
        int j1 = 1 + b0;
        int b1 = x1 > th[j1];
        int j2 = 2 * j1 + 1 + b1;
        int b2 = x2 > th[j2];
        int j3 = 2 * j2 + 1 + b2;
        int b3 = x3 > th[j3];
        int idx = (b0 << 3) | (b1 << 2) | (b2 << 1) | b3;
        int other = __shfl_xor(idx, 1);
        if (!(c & 1))
            idx4[(c >> 1) * N_ROWS + n] = (unsigned char)(idx | (other << 4));
    } else {
        const int i = ((b - N_ROWS) * 256 + t) * 8;
        float4 a = *(const float4*)(lut + i);
        float4 f = *(const float4*)(lut + i + 4);
        uint4 o;
        o.x = f2bf(a.x) | (f2bf(a.y) << 16);
        o.y = f2bf(a.z) | (f2bf(a.w) << 16);
        o.z = f2bf(f.x) | (f2bf(f.y) << 16);
        o.w = f2bf(f.z) | (f2bf(f.w) << 16);
        *(uint4*)(lutb + i) = o;
    }
}

// ---------------- Kernel 2: GEMM with implicit one-hot A ----------------
// out[n][k] = sum_c lut[k][c][idx[n][c]]
// OCCUPANCY PROBE: R10's proven schedule (dual-phase read issue, phase-split
// setprio clusters, counted vmcnt with full-tile prefetch distance, 0 bank
// conflicts) at BM=BN=128 / ni=4 / 40KB LDS -> 4 blocks/CU (vs R10's 2).
// Rationale: MFMA aggregate demand (2483 cy/tile/CU) >> LDS (1024) >> VALU
// (~700); the 97-vs-66us floor gap is barrier-lockstep bubbles. 4 resident
// blocks fill them statistically. R3/R5's 4-block 115us had exposed reads +
// no phase-split (confounded); this isolates the occupancy axis.
#define BM 128
#define BN 128
#define BKT 64          // kdim per LDS stage (2 MFMA K-steps of 32)
#define BSTAGE (BN * BKT * 2)   // 16 KB per B buffer
#define NT (KDIM / BKT)         // 64 tiles

template<bool STAGE_FP32>
__global__ __launch_bounds__(256, 4) void k_gemm(const unsigned short* __restrict__ lutb,
                                                 const float* __restrict__ lutf,
                                                 const unsigned char* __restrict__ idx4,
                                                 float* __restrict__ out) {
    __shared__ unsigned char smem[8192 + 2 * BSTAGE];    // idx 8KB + 2x B 16KB = 40 KB
    unsigned char* ish  = smem;                          // [cbp 64][row 128] (half window)
    unsigned char* bsh0 = smem + 8192;
    unsigned char* bsh1 = smem + 8192 + BSTAGE;

    const int t   = threadIdx.x;
    const int l15 = t & 15;
    const int q   = (t >> 4) & 3;          // quad within wave
    const int w   = t >> 6;
    const int wm  = w >> 1, wn = w & 1;    // 2x2 waves -> 64x64 tile each

    // XCD swizzle: XCD = bid&7 owns 4 consecutive n-panels x all 32 m-blocks.
    const int bid = blockIdx.x;            // 1024 blocks = 32 bx x 32 by
    const int bx  = ((bid & 7) << 2) | ((bid >> 3) & 3);   // n-block 0..31
    const int by  = bid >> 5;                              // m-block 0..31
    const int m0  = by * BM;
    const int n0  = bx * BN;

    // --- idx staging: half hh covers cbp [hh*64, hh*64+64) x rows [m0, m0+128) ---
    auto stageIdx = [&](int hh) {
        #pragma unroll
        for (int qq = 0; qq < 2; qq++) {
            int L = qq * 256 + t;          // 16B chunk: cbp = L>>3, row-part = L&7
            const unsigned char* g = idx4 + (size_t)(hh * 64 + (L >> 3)) * N_ROWS + m0 + (L & 7) * 16;
            __builtin_amdgcn_global_load_lds(
                (const __attribute__((address_space(1))) void*)g,
                (__attribute__((address_space(3))) void*)(ish + L * 16), 16, 0, 0);
        }
    };

    // --- B tile staging: [128 out-rows][64 kdim] bf16, chunk-XOR swizzled ---
    auto stageB = [&](unsigned char* dst, int kbn) {
        #pragma unroll
        for (int qq = 0; qq < 4; qq++) {
            int L = qq * 256 + t;               // 16B chunk index in LDS
            int r = L >> 3, p = L & 7;
            int c = p ^ (r & 7);                // global chunk stored at position p
            const unsigned short* g = lutb + (size_t)(n0 + r) * KDIM + kbn + c * 8;
            __builtin_amdgcn_global_load_lds(
                (const __attribute__((address_space(1))) void*)g,
                (__attribute__((address_space(3))) void*)(dst + L * 16), 16, 0, 0);
        }
    };
    auto stageB32 = [&](unsigned char* dst, int kbn) {
        #pragma unroll
        for (int qq = 0; qq < 4; qq++) {
            int L = qq * 256 + t;
            int r = L >> 3, p = L & 7;
            int c = p ^ (r & 7);
            const float* g = lutf + (size_t)(n0 + r) * KDIM + kbn + c * 8;
            float4 f0 = *(const float4*)g;
            float4 f1 = *(const float4*)(g + 4);
            uint4 o;
            o.x = f2bf(f0.x) | (f2bf(f0.y) << 16);
            o.y = f2bf(f0.z) | (f2bf(f0.w) << 16);
            o.z = f2bf(f1.x) | (f2bf(f1.y) << 16);
            o.w = f2bf(f1.z) | (f2bf(f1.w) << 16);
            *(uint4*)(dst + L * 16) = o;
        }
    };

    f32x4 acc[4][4];
    #pragma unroll
    for (int mi = 0; mi < 4; mi++)
        #pragma unroll
        for (int ni = 0; ni < 4; ni++)
            acc[mi][ni] = (f32x4){0.f, 0.f, 0.f, 0.f};

    const int xorv = l15 & 7;                       // B chunk swizzle key
    const int bRowByte = (wn * 64 + l15) * (BKT * 2);
    const int aByte = wm * 64 + l15 * 4;            // idx word offset within a cbp row
    const int qh4  = (q >> 1) * 4;                  // nibble select: cb c0 vs c0+1
    const unsigned int sub8 = (q & 1) << 3;         // window offset within codebook

    // B fragment reads for phase s: 4 x ds_read_b128 (swizzled chunk)
    auto bfRead = [&](const unsigned char* src, int s, ABFrag (&bf)[4]) {
        const int chunkOff = ((s * 4 + q) ^ xorv) * 16;
        #pragma unroll
        for (int ni = 0; ni < 4; ni++)
            bf[ni].v = *(const bf16x8*)(src + bRowByte + ni * (16 * BKT * 2) + chunkOff);
    };
    // idx word for phase s of tile at kb (half window: slot = cbp & 63)
    auto wRead = [&](int kb, int s) {
        return *(const unsigned int*)(ish + ((((kb >> 5) + s) & 63) * 128) + aByte);
    };
    // per-phase MFMA cluster: build 4 one-hot A frags, 16 MFMAs
    auto mfmaPhase = [&](const ABFrag (&bf)[4], unsigned int w32) {
        ABFrag af[4];
        #pragma unroll
        for (int mi = 0; mi < 4; mi++) {
            unsigned int T = (w32 >> (mi * 8 + qh4)) & 0xFu;
            unsigned int rel = T - sub8;                    // one-hot iff rel in [0,8)
            unsigned long long sh = 0x3F80ull << ((rel & 3) << 4);  // bf16 1.0
            af[mi].u[0] = (rel < 4u) ? sh : 0ull;
            af[mi].u[1] = ((rel - 4u) < 4u) ? sh : 0ull;
        }
        #pragma unroll
        for (int mi = 0; mi < 4; mi++)
            #pragma unroll
            for (int ni = 0; ni < 4; ni++)
                acc[mi][ni] = __builtin_amdgcn_mfma_f32_16x16x32_bf16(
                    af[mi].v, bf[ni].v, acc[mi][ni], 0, 0, 0);
    };

    if (!STAGE_FP32) {
        // prologue: idx-half0(2) + stage0(4) + stage1(4) = 10; vmcnt(4) retires
        // idx + tile0, tile1's 4 stay in flight.
        stageIdx(0);
        stageB(bsh0, 0);
        stageB(bsh1, BKT);
        asm volatile("s_waitcnt vmcnt(4)" ::: "memory");
        __builtin_amdgcn_s_barrier();
        __builtin_amdgcn_sched_barrier(0);

        ABFrag bf0[4], bf1[4];
        for (int tt = 0; tt < NT; tt++) {
            const int kb = tt * BKT;
            unsigned char* cur = (tt & 1) ? bsh1 : bsh0;
            // [A] dual-phase issue: s0 group, pin, s1 group. Compiler inserts
            //     counted lgkm before the s0 cluster.
            unsigned int w0 = wRead(kb, 0);
            bfRead(cur, 0, bf0);
            __builtin_amdgcn_sched_barrier(0);
            bfRead(cur, 1, bf1);
            unsigned int w1 = wRead(kb, 1);
            __builtin_amdgcn_sched_barrier(0);
            // [D0] s0 cluster (s1 reads retire underneath)
            __builtin_amdgcn_s_setprio(1);
            mfmaPhase(bf0, w0);
            __builtin_amdgcn_s_setprio(0);
            asm volatile("s_waitcnt lgkmcnt(0)" ::: "memory");
            __builtin_amdgcn_sched_barrier(0);
            // [B] all waves done reading cur (and, at tt=31, ish half0) -> overwrite safe
            __builtin_amdgcn_s_barrier();
            __builtin_amdgcn_sched_barrier(0);
            // [C] restage: idx half1 first at tt=31 (so [E]'s vmcnt(4) retires it),
            //     then B tile tt+2 (issue only)
            if (tt == 31) stageIdx(1);
            if (tt + 2 < NT) stageB(cur, kb + 2 * BKT);
            __builtin_amdgcn_sched_barrier(0);
            // [D1] s1 cluster (staging loads fly underneath)
            __builtin_amdgcn_s_setprio(1);
            mfmaPhase(bf1, w1);
            __builtin_amdgcn_s_setprio(0);
            // [E] counted wait: tile tt+1's 4 loads (issued a full tile ago, plus
            //     idx half1 at tt=31) done; tt+2's 4 newest stay in flight
            if (tt + 2 < NT) asm volatile("s_waitcnt vmcnt(4)" ::: "memory");
            else             asm volatile("s_waitcnt vmcnt(0)" ::: "memory");
            // [F] staging writes visible to all waves before next iteration reads
            __builtin_amdgcn_s_barrier();
            __builtin_amdgcn_sched_barrier(0);
        }
    } else {
        // Fallback (no workspace for lutb): single-buffer loop, convert on stage.
        stageIdx(0);
        asm volatile("s_waitcnt vmcnt(0)" ::: "memory");
        __syncthreads();
        ABFrag bfx[4];
        for (int tt = 0; tt < NT; tt++) {
            const int kb = tt * BKT;
            if (tt == 32) stageIdx(1);          // prev sync: no readers of ish in flight
            stageB32(bsh0, kb);
            __syncthreads();
            #pragma unroll
            for (int s = 0; s < 2; s++) {
                bfRead(bsh0, s, bfx);
                mfmaPhase(bfx, wRead(kb, s));
            }
            __syncthreads();
        }
    }

    // --- epilogue: MFMA row m = q*4 + r -> global row = m0 + wm*64 + 4*m + mi ---
    #pragma unroll
    for (int mi = 0; mi < 4; mi++) {
        #pragma unroll
        for (int ni = 0; ni < 4; ni++) {
            const int col = n0 + wn * 64 + ni * 16 + l15;
            #pragma unroll
            for (int r = 0; r < 4; r++) {
                const int row = m0 + wm * 64 + 4 * (q * 4 + r) + mi;
                out[(size_t)row * OUT_F + col] = acc[mi][ni][r];
            }
        }
    }
}

extern "C" void kernel_launch(void* const* d_in, const int* in_sizes, int n_in,
                              void* d_out, int out_size, void* d_ws, size_t ws_size,
                              hipStream_t stream) {
    const float* input = (const float*)d_in[0];
    const int*   dims  = (const int*)d_in[1];
    // d_in[2] selection_matrix, d_in[4] tree_des_mat: structure folded into the kernels
    const float* thr   = (const float*)d_in[3];
    const float* lut   = (const float*)d_in[5];
    float* out = (float*)d_out;

    const size_t lutbBytes = (size_t)OUT_F * KDIM * 2;       // 32 MB
    const size_t idxBytes  = (size_t)(C_CB / 2) * N_ROWS;    // 512 KB

    const int nblocks = (OUT_F / BN) * (N_ROWS / BM);        // 32 x 32 = 1024

    if (ws_size >= lutbBytes + idxBytes) {
        unsigned short* lutb = (unsigned short*)d_ws;
        unsigned char*  idx4 = (unsigned char*)d_ws + lutbBytes;
        k_prep<<<N_ROWS + CVT_BLOCKS, 256, 0, stream>>>(input, dims, thr, idx4, lut, lutb);
        k_gemm<false><<<nblocks, 256, 0, stream>>>(lutb, lut, idx4, out);
    } else {
        unsigned char* idx4 = (unsigned char*)d_ws;
        k_prep<<<N_ROWS, 256, 0, stream>>>(input, dims, thr, idx4, lut, nullptr);
        k_gemm<true><<<nblocks, 256, 0, stream>>>(nullptr, lut, idx4, out);
    }
}

// Round 12
// 281.434 us; speedup vs baseline: 1.0758x; 1.0758x over previous
//
#include <hip/hip_runtime.h>

#define N_ROWS 4096
#define IN_F   4096
#define OUT_F  4096
#define C_CB   256
#define KDIM   4096   // C_CB * 16

typedef short bf16x8 __attribute__((ext_vector_type(8)));
typedef float f32x4  __attribute__((ext_vector_type(4)));

union ABFrag { unsigned long long u[2]; bf16x8 v; };

__device__ __forceinline__ unsigned int f2bf(float f) {
    unsigned int u = __builtin_bit_cast(unsigned int, f);
    return (u + 0x7FFFu + ((u >> 16) & 1u)) >> 16;   // RNE
}

// ---------------- Kernel 1: fused prep ----------------
// blocks [0, N_ROWS): tree descent, R3-proven LDS-staged gather form
// blocks [N_ROWS, N_ROWS+CVT_BLOCKS): lut fp32 -> bf16
#define CVT_BLOCKS ((OUT_F * KDIM) / (256 * 8))   // 8192

__global__ __launch_bounds__(256) void k_prep(const float* __restrict__ input,
                                              const int* __restrict__ dims,
                                              const float* __restrict__ thr,
                                              unsigned char* __restrict__ idx4,
                                              const float* __restrict__ lut,
                                              unsigned short* __restrict__ lutb) {
    __shared__ float rowS[IN_F];         // 16 KB
    __shared__ float thrS[C_CB * 15];    // 15 KB
    __shared__ int   dimS[C_CB * 4];     // 4 KB
    const int b = blockIdx.x;
    const int t = threadIdx.x;

    if (b < N_ROWS) {
        const int n = b;
        #pragma unroll
        for (int i = 0; i < 4; i++) dimS[i * 256 + t] = dims[i * 256 + t];
        #pragma unroll
        for (int i = 0; i < 15; i++) thrS[i * 256 + t] = thr[i * 256 + t];
        const float* row = input + (size_t)n * IN_F;
        #pragma unroll
        for (int i = 0; i < 4; i++) {
            float4 v = *(const float4*)(row + i * 1024 + t * 4);
            *(float4*)(rowS + i * 1024 + t * 4) = v;
        }
        __syncthreads();

        const int c = t;
        int4 d = *(const int4*)(dimS + c * 4);
        const float* th = thrS + c * 15;
        float x0 = rowS[d.x], x1 = rowS[d.y], x2 = rowS[d.z], x3 = rowS[d.w];
        int b0 = x0 > th[0];
        int j1 = 1 + b0;
        int b1 = x1 > th[j1];
        int j2 = 2 * j1 + 1 + b1;
        int b2 = x2 > th[j2];
        int j3 = 2 * j2 + 1 + b2;
        int b3 = x3 > th[j3];
        int idx = (b0 << 3) | (b1 << 2) | (b2 << 1) | b3;
        int other = __shfl_xor(idx, 1);
        if (!(c & 1))
            idx4[(c >> 1) * N_ROWS + n] = (unsigned char)(idx | (other << 4));
    } else {
        const int i = ((b - N_ROWS) * 256 + t) * 8;
        float4 a = *(const float4*)(lut + i);
        float4 f = *(const float4*)(lut + i + 4);
        uint4 o;
        o.x = f2bf(a.x) | (f2bf(a.y) << 16);
        o.y = f2bf(a.z) | (f2bf(a.w) << 16);
        o.z = f2bf(f.x) | (f2bf(f.y) << 16);
        o.w = f2bf(f.z) | (f2bf(f.w) << 16);
        *(uint4*)(lutb + i) = o;
    }
}

// ---------------- Kernel 2: GEMM with implicit one-hot A ----------------
// out[n][k] = sum_c lut[k][c][idx[n][c]]
// R10 proven skeleton (97us: dual-phase read issue, counted vmcnt(8), two
// barriers/tile, 0 bank conflicts, ni=8 @ 2 blocks/CU — register-file bound,
// R11 falsified more blocks). This round's single delta: PURE-MFMA setprio
// clusters — A-builds hoisted OUT of the prio windows. w0/w1 read first in
// [A] (earliest counted-lgkm retirement); s0's af built before the cluster
// (overlaps in-flight b128 reads); s1's af built in the [C] region (w1
// already retired). af0 dead before af1 built -> no VGPR growth.
#define BM 128
#define BN 256
#define BKT 64          // kdim per LDS stage (2 MFMA K-steps of 32)
#define BSTAGE (BN * BKT * 2)   // 32 KB per B buffer
#define NT (KDIM / BKT)         // 64 tiles

template<bool STAGE_FP32>
__global__ __launch_bounds__(256, 2) void k_gemm(const unsigned short* __restrict__ lutb,
                                                 const float* __restrict__ lutf,
                                                 const unsigned char* __restrict__ idx4,
                                                 float* __restrict__ out) {
    __shared__ unsigned char smem[16384 + 2 * BSTAGE];   // idx 16KB + 2x B 32KB = 80 KB
    unsigned char* ish  = smem;                          // [cbp 128][row 128]
    unsigned char* bsh0 = smem + 16384;
    unsigned char* bsh1 = smem + 16384 + BSTAGE;

    const int t   = threadIdx.x;
    const int l15 = t & 15;
    const int q   = (t >> 4) & 3;          // quad within wave
    const int w   = t >> 6;
    const int wm  = w >> 1, wn = w & 1;    // 2x2 waves -> 64x128 tile each

    // XCD swizzle: XCD = bid&7 owns 2 consecutive n-panels x all 32 m-blocks.
    const int bid = blockIdx.x;            // 512 blocks = 16 bx x 32 by
    const int bx  = ((bid & 7) << 1) | ((bid >> 3) & 1);   // n-block 0..15
    const int by  = bid >> 4;                              // m-block 0..31
    const int m0  = by * BM;
    const int n0  = bx * BN;

    // --- idx staging: full [cbp 128][row 128] window, once in prologue ---
    auto stageIdx = [&]() {
        #pragma unroll
        for (int qq = 0; qq < 4; qq++) {
            int L = qq * 256 + t;          // 16B chunk: cbp = L>>3, row-part = L&7
            const unsigned char* g = idx4 + (size_t)(L >> 3) * N_ROWS + m0 + (L & 7) * 16;
            __builtin_amdgcn_global_load_lds(
                (const __attribute__((address_space(1))) void*)g,
                (__attribute__((address_space(3))) void*)(ish + L * 16), 16, 0, 0);
        }
    };

    // --- B tile staging: [256 out-rows][64 kdim] bf16, chunk-XOR swizzled ---
    auto stageB = [&](unsigned char* dst, int kbn) {
        #pragma unroll
        for (int qq = 0; qq < 8; qq++) {
            int L = qq * 256 + t;               // 16B chunk index in LDS
            int r = L >> 3, p = L & 7;
            int c = p ^ (r & 7);                // global chunk stored at position p
            const unsigned short* g = lutb + (size_t)(n0 + r) * KDIM + kbn + c * 8;
            __builtin_amdgcn_global_load_lds(
                (const __attribute__((address_space(1))) void*)g,
                (__attribute__((address_space(3))) void*)(dst + L * 16), 16, 0, 0);
        }
    };
    auto stageB32 = [&](unsigned char* dst, int kbn) {
        #pragma unroll
        for (int qq = 0; qq < 8; qq++) {
            int L = qq * 256 + t;
            int r = L >> 3, p = L & 7;
            int c = p ^ (r & 7);
            const float* g = lutf + (size_t)(n0 + r) * KDIM + kbn + c * 8;
            float4 f0 = *(const float4*)g;
            float4 f1 = *(const float4*)(g + 4);
            uint4 o;
            o.x = f2bf(f0.x) | (f2bf(f0.y) << 16);
            o.y = f2bf(f0.z) | (f2bf(f0.w) << 16);
            o.z = f2bf(f1.x) | (f2bf(f1.y) << 16);
            o.w = f2bf(f1.z) | (f2bf(f1.w) << 16);
            *(uint4*)(dst + L * 16) = o;
        }
    };

    f32x4 acc[4][8];
    #pragma unroll
    for (int mi = 0; mi < 4; mi++)
        #pragma unroll
        for (int ni = 0; ni < 8; ni++)
            acc[mi][ni] = (f32x4){0.f, 0.f, 0.f, 0.f};

    const int xorv = l15 & 7;                       // B chunk swizzle key
    const int bRowByte = (wn * 128 + l15) * (BKT * 2);
    const int aByte = wm * 64 + l15 * 4;            // idx word offset within a cbp row
    const int qh4  = (q >> 1) * 4;                  // nibble select: cb c0 vs c0+1
    const unsigned int sub8 = (q & 1) << 3;         // window offset within codebook

    // B fragment reads for phase s: 8 x ds_read_b128 (swizzled chunk)
    auto bfRead = [&](const unsigned char* src, int s, ABFrag (&bf)[8]) {
        const int chunkOff = ((s * 4 + q) ^ xorv) * 16;
        #pragma unroll
        for (int ni = 0; ni < 8; ni++)
            bf[ni].v = *(const bf16x8*)(src + bRowByte + ni * (16 * BKT * 2) + chunkOff);
    };
    // idx word for phase s of tile at kb (full window: cbp in [0,128))
    auto wRead = [&](int kb, int s) {
        return *(const unsigned int*)(ish + ((kb >> 5) + s) * 128 + aByte);
    };
    // A-build: 4 one-hot fragments from one idx word (pure VALU, ~48 ops)
    auto buildAf = [&](ABFrag (&af)[4], unsigned int w32) {
        #pragma unroll
        for (int mi = 0; mi < 4; mi++) {
            unsigned int T = (w32 >> (mi * 8 + qh4)) & 0xFu;
            unsigned int rel = T - sub8;                    // one-hot iff rel in [0,8)
            unsigned long long sh = 0x3F80ull << ((rel & 3) << 4);  // bf16 1.0
            af[mi].u[0] = (rel < 4u) ? sh : 0ull;
            af[mi].u[1] = ((rel - 4u) < 4u) ? sh : 0ull;
        }
    };
    // pure-MFMA cluster: 32 MFMAs, no VALU
    auto mfmaOnly = [&](const ABFrag (&bf)[8], const ABFrag (&af)[4]) {
        #pragma unroll
        for (int mi = 0; mi < 4; mi++)
            #pragma unroll
            for (int ni = 0; ni < 8; ni++)
                acc[mi][ni] = __builtin_amdgcn_mfma_f32_16x16x32_bf16(
                    af[mi].v, bf[ni].v, acc[mi][ni], 0, 0, 0);
    };

    if (!STAGE_FP32) {
        // prologue: idx(4) + stage0(8) + stage1(8) = 20 issued; vmcnt(8) retires
        // the 12 oldest (idx + tile0), tile1's 8 stay in flight.
        stageIdx();
        stageB(bsh0, 0);
        stageB(bsh1, BKT);
        asm volatile("s_waitcnt vmcnt(8)" ::: "memory");
        __builtin_amdgcn_s_barrier();
        __builtin_amdgcn_sched_barrier(0);

        ABFrag bf0[8], bf1[8];
        for (int tt = 0; tt < NT; tt++) {
            const int kb = tt * BKT;
            unsigned char* cur = (tt & 1) ? bsh1 : bsh0;
            // [A] w words FIRST (earliest counted-lgkm retirement), then both
            //     phases' frag groups pinned in order.
            unsigned int w0 = wRead(kb, 0);
            unsigned int w1 = wRead(kb, 1);
            bfRead(cur, 0, bf0);
            __builtin_amdgcn_sched_barrier(0);
            bfRead(cur, 1, bf1);
            __builtin_amdgcn_sched_barrier(0);
            // [V0] build s0 af OUTSIDE the prio window; compiler's counted lgkm
            //      wait covers only w0 — build overlaps in-flight b128 reads.
            ABFrag af0[4];
            buildAf(af0, w0);
            // [D0] pure-MFMA cluster (s1 reads retire underneath)
            __builtin_amdgcn_s_setprio(1);
            mfmaOnly(bf0, af0);
            __builtin_amdgcn_s_setprio(0);
            // all reads of cur retired before other waves may overwrite it
            asm volatile("s_waitcnt lgkmcnt(0)" ::: "memory");
            __builtin_amdgcn_sched_barrier(0);
            // [B] all waves done reading cur -> overwrite safe
            __builtin_amdgcn_s_barrier();
            __builtin_amdgcn_sched_barrier(0);
            // [C] restage cur with tile tt+2 (issue only; no wait here)
            if (tt + 2 < NT) stageB(cur, kb + 2 * BKT);
            __builtin_amdgcn_sched_barrier(0);
            // [V1] build s1 af (w1 retired by the pre-[B] lgkm0; pure VALU here
            //      overlaps the staging issue, outside the prio window)
            ABFrag af1[4];
            buildAf(af1, w1);
            // [D1] pure-MFMA cluster (staging loads fly underneath)
            __builtin_amdgcn_s_setprio(1);
            mfmaOnly(bf1, af1);
            __builtin_amdgcn_s_setprio(0);
            // [E] counted wait: tile tt+1's 8 loads done (issued a full tile ago);
            //     tt+2's 8 newest stay in flight
            if (tt + 2 < NT) asm volatile("s_waitcnt vmcnt(8)" ::: "memory");
            else             asm volatile("s_waitcnt vmcnt(0)" ::: "memory");
            // [F] staging writes visible to all waves before next iteration reads
            __builtin_amdgcn_s_barrier();
            __builtin_amdgcn_sched_barrier(0);
        }
    } else {
        // Fallback (no workspace for lutb): single-buffer loop, convert on stage.
        stageIdx();
        asm volatile("s_waitcnt vmcnt(0)" ::: "memory");
        __syncthreads();
        ABFrag bfx[8], afx[4];
        for (int tt = 0; tt < NT; tt++) {
            const int kb = tt * BKT;
            stageB32(bsh0, kb);
            __syncthreads();
            #pragma unroll
            for (int s = 0; s < 2; s++) {
                bfRead(bsh0, s, bfx);
                buildAf(afx, wRead(kb, s));
                mfmaOnly(bfx, afx);
            }
            __syncthreads();
        }
    }

    // --- epilogue: MFMA row m = q*4 + r -> global row = m0 + wm*64 + 4*m + mi ---
    #pragma unroll
    for (int mi = 0; mi < 4; mi++) {
        #pragma unroll
        for (int ni = 0; ni < 8; ni++) {
            const int col = n0 + wn * 128 + ni * 16 + l15;
            #pragma unroll
            for (int r = 0; r < 4; r++) {
                const int row = m0 + wm * 64 + 4 * (q * 4 + r) + mi;
                out[(size_t)row * OUT_F + col] = acc[mi][ni][r];
            }
        }
    }
}

extern "C" void kernel_launch(void* const* d_in, const int* in_sizes, int n_in,
                              void* d_out, int out_size, void* d_ws, size_t ws_size,
                              hipStream_t stream) {
    const float* input = (const float*)d_in[0];
    const int*   dims  = (const int*)d_in[1];
    // d_in[2] selection_matrix, d_in[4] tree_des_mat: structure folded into the kernels
    const float* thr   = (const float*)d_in[3];
    const float* lut   = (const float*)d_in[5];
    float* out = (float*)d_out;

    const size_t lutbBytes = (size_t)OUT_F * KDIM * 2;       // 32 MB
    const size_t idxBytes  = (size_t)(C_CB / 2) * N_ROWS;    // 512 KB

    const int nblocks = (OUT_F / BN) * (N_ROWS / BM);        // 16 x 32 = 512

    if (ws_size >= lutbBytes + idxBytes) {
        unsigned short* lutb = (unsigned short*)d_ws;
        unsigned char*  idx4 = (unsigned char*)d_ws + lutbBytes;
        k_prep<<<N_ROWS + CVT_BLOCKS, 256, 0, stream>>>(input, dims, thr, idx4, lut, lutb);
        k_gemm<false><<<nblocks, 256, 0, stream>>>(lutb, lut, idx4, out);
    } else {
        unsigned char* idx4 = (unsigned char*)d_ws;
        k_prep<<<N_ROWS, 256, 0, stream>>>(input, dims, thr, idx4, lut, nullptr);
        k_gemm<true><<<nblocks, 256, 0, stream>>>(nullptr, lut, idx4, out);
    }
}